// Round 6
// baseline (139.386 us; speedup 1.0000x reference)
//
#include <hip/hip_runtime.h>
#include <hip/hip_bf16.h>
#include <math.h>

#define B_ 2
#define NCLS_ 19
#define N_ 25600
#define C_ 256
#define MAXN_ 1024
#define THRESH_ 100
#define MAXSAMP_ 1024
#define NLIST_ (B_*NCLS_*2)
#define NHIST_ (B_*NCLS_)
#define NBLK_ 200              // (B_*N_+255)/256
#define CAP_ 6144
#define NRF_ 32    // feat key ranges (MAXN/32)
#define NRM_ 96    // mask key ranges (3*MAXN/32)

typedef __attribute__((ext_vector_type(8))) short bf16x8;
typedef __attribute__((ext_vector_type(4))) float f32x4;

// ---------------- workspace layout (bytes) ----------------
constexpr size_t OFF_PREDICT = 0;                                   // B*N int
constexpr size_t OFF_PROBC   = OFF_PREDICT + (size_t)B_*N_*4;       // B*N float
constexpr size_t OFF_CNT     = OFF_PROBC + (size_t)B_*N_*4;         // cnt_all[38]+cnt_easy[38]
constexpr size_t OFF_META    = OFF_CNT + 1024;
constexpr size_t OFF_PAIRS   = OFF_META + 256;
constexpr size_t OFF_SELB    = OFF_PAIRS + 1024;
constexpr size_t OFF_SELP    = OFF_SELB + (size_t)MAXN_*4;
constexpr size_t OFF_SELL    = OFF_SELP + (size_t)MAXN_*4;
constexpr size_t OFF_SFH     = OFF_SELL + (size_t)MAXN_*4;          // MAXN*C bf16 (aliased by CAND pre-gather)
constexpr size_t OFF_KMH     = OFF_SFH + (size_t)MAXN_*C_*2;        // 3*MAXN*C bf16
constexpr size_t OFF_PAF     = OFF_KMH + (size_t)3*MAXN_*C_*2;
constexpr size_t OFF_PAM     = OFF_PAF + (size_t)MAXN_*4;
constexpr size_t OFF_LBASE   = OFF_PAM + (size_t)MAXN_*4;
constexpr size_t OFF_CURS    = OFF_LBASE + 512;
constexpr size_t OFF_HISTA   = OFF_CURS + 512;                      // NBLK*NHIST int
constexpr size_t OFF_HISTE   = OFF_HISTA + (size_t)NBLK_*NHIST_*4;  // NBLK*NHIST int
constexpr size_t OFF_PFP     = OFF_HISTE + (size_t)NBLK_*NHIST_*4;  // MAXN*NRF float4
constexpr size_t OFF_PMP     = OFF_PFP + (size_t)MAXN_*NRF_*16;     // MAXN*NRM float4
constexpr size_t OFF_END     = OFF_PMP + (size_t)MAXN_*NRM_*16;
constexpr size_t OFF_CAND    = OFF_SFH;   // candidate keys (B*N u64 = 400KB <= 512KB SFH)

__device__ __forceinline__ unsigned short f2bf(float x) {
    unsigned u = __float_as_uint(x);
    unsigned r = (u + 0x7FFFu + ((u >> 16) & 1u)) >> 16;   // RNE
    return (unsigned short)r;
}

// ---------------- 1. softmax / argmax / per-block histograms (no global atomics) ----------------
__global__ void k_softmax_predict(const float* __restrict__ seg, const int* __restrict__ gt,
                                  int* __restrict__ predict, float* __restrict__ probc,
                                  int* __restrict__ hista, int* __restrict__ histe) {
    __shared__ int h_all[NHIST_];
    __shared__ int h_easy[NHIST_];
    int t = threadIdx.x;
    if (t < NHIST_) { h_all[t] = 0; h_easy[t] = 0; }
    __syncthreads();
    int idx = blockIdx.x * blockDim.x + t;
    if (idx < B_*N_) {
        int b = idx / N_, p = idx - b*N_;
        const float* base = seg + (size_t)b*NCLS_*N_ + p;
        float v[NCLS_];
        float mx = base[0]; v[0] = mx; int am = 0;
        for (int k = 1; k < NCLS_; ++k) {
            float x = base[(size_t)k*N_];
            v[k] = x;
            if (x > mx) { mx = x; am = k; }
        }
        float s = 0.f;
        for (int k = 0; k < NCLS_; ++k) s += expf(v[k] - mx);
        int lab = gt[idx];
        float pv = 0.f;
        if (lab >= 0 && lab < NCLS_) {
            pv = expf(v[lab] - mx) / s;
            atomicAdd(&h_all[b*NCLS_ + lab], 1);
            if (am == lab) atomicAdd(&h_easy[b*NCLS_ + lab], 1);
        }
        predict[idx] = am;
        probc[idx] = pv;
    }
    __syncthreads();
    if (t < NHIST_) {
        hista[blockIdx.x*NHIST_ + t] = h_all[t];
        histe[blockIdx.x*NHIST_ + t] = h_easy[t];
    }
}

// ---------------- 2. reduce histograms + mining plan (1 block) ----------------
__global__ void k_plan(const int* __restrict__ hista, const int* __restrict__ histe,
                       int* __restrict__ cnt_all, int* __restrict__ cnt_easy,
                       int* __restrict__ meta, int* __restrict__ pairs,
                       int* __restrict__ lbase, int* __restrict__ cursor) {
    int t = threadIdx.x;
    if (t < NHIST_) {
        int sa = 0, se = 0;
        for (int blk = 0; blk < NBLK_; ++blk) {
            sa += hista[blk*NHIST_ + t];
            se += histe[blk*NHIST_ + t];
        }
        cnt_all[t] = sa; cnt_easy[t] = se;
    }
    if (t < NLIST_) cursor[t] = 0;
    __syncthreads();
    if (t != 0) return;
    int total = 0;
    for (int i = 0; i < NHIST_; ++i) if (cnt_all[i] > THRESH_) total++;
    meta[0] = total;
    int n_view = 0;
    if (total > 0) { n_view = MAXSAMP_ / total; if (n_view > THRESH_) n_view = THRESH_; }
    meta[1] = n_view;
    int off = 0;
    for (int i = 0; i < NHIST_; ++i) {
        int q = (cnt_all[i] > THRESH_) ? 1 : 0;
        int h_take = 0, e_take = 0;
        if (q) {
            int ne = cnt_easy[i];
            int nh = cnt_all[i] - ne;
            int nhk, nek;
            bool hb = 2*nh >= n_view, eb = 2*ne >= n_view;
            if (hb && eb)      { nhk = n_view/2; nek = n_view - nhk; }
            else if (hb)       { nek = ne;       nhk = n_view - nek; }
            else if (eb)       { nhk = nh;       nek = n_view - nhk; }
            else               { nhk = nh;       nek = ne; }
            h_take = nhk < nh ? nhk : nh;
            e_take = nek < ne ? nek : ne;
        }
        pairs[4*i+0] = q; pairs[4*i+1] = h_take; pairs[4*i+2] = e_take; pairs[4*i+3] = off;
        off += h_take + e_take;
    }
    meta[2] = off;
    int run = 0;
    for (int i = 0; i < NHIST_; ++i) {
        int ne = cnt_easy[i];
        int nh = cnt_all[i] - ne;
        lbase[2*i+0] = run; run += ne;   // easy list
        lbase[2*i+1] = run; run += nh;   // hard list
    }
}

// ---------------- 3a. compact candidates (LDS-aggregated atomics) ----------------
__global__ void k_scatter(const int* __restrict__ gt, const int* __restrict__ predict,
                          const float* __restrict__ probc, const int* __restrict__ lbase,
                          int* __restrict__ cursor, unsigned long long* __restrict__ cand) {
    __shared__ int lcnt[NLIST_];
    __shared__ int lbeg[NLIST_];
    int t = threadIdx.x;
    if (t < NLIST_) lcnt[t] = 0;
    __syncthreads();
    int idx = blockIdx.x * blockDim.x + t;
    int L = -1, lp = 0;
    unsigned long long key = 0;
    if (idx < B_*N_) {
        int lab = gt[idx];
        if (lab >= 0 && lab < NCLS_) {
            int b = idx / N_, p = idx - b*N_;
            int ishard = (predict[idx] != lab) ? 1 : 0;
            L = (b*NCLS_ + lab)*2 + ishard;
            lp = atomicAdd(&lcnt[L], 1);
            unsigned int pb = __float_as_uint(probc[idx]);
            unsigned int lo = ishard ? (0xFFFFFFFFu - (unsigned int)p) : (unsigned int)p;
            key = ((unsigned long long)pb << 32) | (unsigned long long)lo;
        }
    }
    __syncthreads();
    if (t < NLIST_ && lcnt[t] > 0) lbeg[t] = atomicAdd(&cursor[t], lcnt[t]);
    __syncthreads();
    if (L >= 0) cand[(size_t)lbase[L] + lbeg[L] + lp] = key;
}

// ---------------- 3b. exact ordered top-k per list (wave-reduce) ----------------
__global__ void k_select2(const int* __restrict__ cnt_all, const int* __restrict__ cnt_easy,
                          const int* __restrict__ pairs, const int* __restrict__ lbase,
                          const unsigned long long* __restrict__ cand,
                          int* __restrict__ sel_b, int* __restrict__ sel_p, int* __restrict__ sel_l) {
    __shared__ unsigned long long keys[CAP_];
    __shared__ unsigned long long wpart[2][4];
    int bid = blockIdx.x;
    int slot = bid >> 1, ishard = bid & 1;
    if (!pairs[4*slot]) return;
    int h_take = pairs[4*slot+1], e_take = pairs[4*slot+2];
    int take = ishard ? h_take : e_take;
    if (take == 0) return;
    int off = pairs[4*slot+3] + (ishard ? 0 : h_take);
    int ne = cnt_easy[slot];
    int m = ishard ? (cnt_all[slot] - ne) : ne;
    int L = slot*2 + ishard;
    const unsigned long long* g = cand + lbase[L];
    int t = threadIdx.x, lane = t & 63, w = t >> 6;
    bool fits = (m <= CAP_);
    if (fits) {
        for (int j = t; j < m; j += 256) keys[j] = g[j];
        __syncthreads();
    }
    int b = slot / NCLS_, c = slot - b*NCLS_;
    unsigned long long prev = ishard ? 0xFFFFFFFFFFFFFFFFull : 0ull;
    for (int it = 0; it < take; ++it) {
        unsigned long long best = ishard ? 0ull : 0xFFFFFFFFFFFFFFFFull;
        if (ishard) {
            for (int j = t; j < m; j += 256) {
                unsigned long long k = fits ? keys[j] : g[j];
                if (k < prev && k > best) best = k;
            }
        } else {
            for (int j = t; j < m; j += 256) {
                unsigned long long k = fits ? keys[j] : g[j];
                if (k > prev && k < best) best = k;
            }
        }
        #pragma unroll
        for (int d = 1; d < 64; d <<= 1) {
            unsigned long long o = __shfl_xor(best, d);
            if (ishard ? (o > best) : (o < best)) best = o;
        }
        if (lane == 0) wpart[it & 1][w] = best;
        __syncthreads();
        unsigned long long b0 = wpart[it & 1][0], b1 = wpart[it & 1][1];
        unsigned long long b2 = wpart[it & 1][2], b3 = wpart[it & 1][3];
        if (ishard) {
            unsigned long long hi01 = b0 > b1 ? b0 : b1;
            unsigned long long hi23 = b2 > b3 ? b2 : b3;
            prev = hi01 > hi23 ? hi01 : hi23;
        } else {
            unsigned long long lo01 = b0 < b1 ? b0 : b1;
            unsigned long long lo23 = b2 < b3 ? b2 : b3;
            prev = lo01 < lo23 ? lo01 : lo23;
        }
        if (t == 0) {
            unsigned int lo = (unsigned int)(prev & 0xFFFFFFFFull);
            int p = ishard ? (int)(0xFFFFFFFFu - lo) : (int)lo;
            sel_b[off+it] = b; sel_p[off+it] = p; sel_l[off+it] = c;
        }
    }
}

// ---------------- 4. gather + l2-normalize -> bf16 rows (single barrier) ----------------
__global__ void k_gather(const float* __restrict__ pf, const float* __restrict__ pm,
                         const int* __restrict__ meta, const int* __restrict__ sel_b,
                         const int* __restrict__ sel_p,
                         unsigned short* __restrict__ sfh, unsigned short* __restrict__ km) {
    __shared__ float wpart[4][4];   // [wave][vec]
    int s = blockIdx.x;
    int n = meta[2];
    if (s >= n) return;
    int b = sel_b[s], p = sel_p[s];
    int t = threadIdx.x, lane = t & 63, w = t >> 6;
    float x0 = pf[((size_t)(b*C_ + t))*N_ + p];               // feat
    float x1 = pm[((size_t)((2*B_ + b)*C_ + t))*N_ + p];      // anchor (masks[-1])
    float x2 = pm[((size_t)((0*B_ + b)*C_ + t))*N_ + p];      // key 0
    float x3 = pm[((size_t)((1*B_ + b)*C_ + t))*N_ + p];      // key 1
    float s0 = x0*x0, s1 = x1*x1, s2 = x2*x2, s3 = x3*x3;
    #pragma unroll
    for (int d = 1; d < 64; d <<= 1) {
        s0 += __shfl_xor(s0, d);
        s1 += __shfl_xor(s1, d);
        s2 += __shfl_xor(s2, d);
        s3 += __shfl_xor(s3, d);
    }
    if (lane == 0) { wpart[w][0] = s0; wpart[w][1] = s1; wpart[w][2] = s2; wpart[w][3] = s3; }
    __syncthreads();
    float t0 = wpart[0][0] + wpart[1][0] + wpart[2][0] + wpart[3][0];
    float t1 = wpart[0][1] + wpart[1][1] + wpart[2][1] + wpart[3][1];
    float t2 = wpart[0][2] + wpart[1][2] + wpart[2][2] + wpart[3][2];
    float t3 = wpart[0][3] + wpart[1][3] + wpart[2][3] + wpart[3][3];
    sfh[(size_t)s*C_ + t]             = f2bf(x0 / fmaxf(sqrtf(t0), 1e-12f));
    km[(size_t)s*C_ + t]              = f2bf(x1 / fmaxf(sqrtf(t1), 1e-12f));
    km[(size_t)(n + 2*s + 0)*C_ + t]  = f2bf(x2 / fmaxf(sqrtf(t2), 1e-12f));
    km[(size_t)(n + 2*s + 1)*C_ + t]  = f2bf(x3 / fmaxf(sqrtf(t3), 1e-12f));
}

// ---------------- 5. fused MFMA GEMM + masked-softmax partials ----------------
// blockIdx.y < 16 : feat  (A=B=sfh, M=n,  part=pfp, NR=32)
// blockIdx.y >= 16: mask  (A=B=km,  M=3n, part=pmp, NR=96)
// Block = 64x64 tile, 4 waves in 2x2, each wave 32x32 via 2x2 mfma_f32_16x16x32_bf16.
__global__ void __launch_bounds__(256, 4)
k_rows_mfma(const int* __restrict__ meta, const unsigned short* __restrict__ sfh,
            const unsigned short* __restrict__ km, const int* __restrict__ sel_l,
            float4* __restrict__ pfp, float4* __restrict__ pmp) {
    const int n = meta[2];
    const bool maskmode = (blockIdx.y >= 16);
    const int yb = maskmode ? (blockIdx.y - 16) : blockIdx.y;
    const int M = maskmode ? 3*n : n;
    const int rbase = blockIdx.x * 64;
    const int cbase = yb * 64;
    if (rbase >= n || cbase >= M) return;
    const unsigned short* buf = maskmode ? km : sfh;
    float4* part = maskmode ? pmp : pfp;
    const int NR = maskmode ? NRM_ : NRF_;

    __shared__ int sl[MAXN_];
    const int t = threadIdx.x;
    for (int j = t; j < n; j += 256) sl[j] = sel_l[j];
    __syncthreads();

    const int wid = t >> 6, lane = t & 63;
    const int wr = wid >> 1, wc = wid & 1;
    const int r0 = rbase + wr*32;
    const int c0 = cbase + wc*32;
    const int lrow = lane & 15, lk = (lane >> 4) * 8;

    const bf16x8 zero8 = {0,0,0,0,0,0,0,0};
    f32x4 acc[2][2];
    #pragma unroll
    for (int i = 0; i < 2; ++i)
        #pragma unroll
        for (int j = 0; j < 2; ++j) acc[i][j] = (f32x4){0.f,0.f,0.f,0.f};

    for (int kk = 0; kk < C_; kk += 32) {
        bf16x8 af[2], bfr[2];
        #pragma unroll
        for (int i = 0; i < 2; ++i) {
            int r = r0 + i*16 + lrow;
            af[i] = (r < n) ? *(const bf16x8*)&buf[(size_t)r*C_ + kk + lk] : zero8;
        }
        #pragma unroll
        for (int j = 0; j < 2; ++j) {
            int c = c0 + j*16 + lrow;
            bfr[j] = (c < M) ? *(const bf16x8*)&buf[(size_t)c*C_ + kk + lk] : zero8;
        }
        #pragma unroll
        for (int i = 0; i < 2; ++i)
            #pragma unroll
            for (int j = 0; j < 2; ++j)
                acc[i][j] = __builtin_amdgcn_mfma_f32_16x16x32_bf16(af[i], bfr[j], acc[i][j], 0, 0, 0);
    }

    // epilogue: C[r][c] layout: col = lane&15 (+j*16), row = (lane>>4)*4 + reg (+i*16)
    const int ri = yb*2 + wc;
    const int g4 = (lane >> 4) * 4;
    const int lc = lane & 15;
    #pragma unroll
    for (int i = 0; i < 2; ++i) {
        #pragma unroll
        for (int q = 0; q < 4; ++q) {
            int row = r0 + i*16 + g4 + q;
            bool rok = (row < n);
            int la = rok ? sl[row] : 0;
            float v0 = acc[i][0][q] * 10.0f;
            float v1 = acc[i][1][q] * 10.0f;
            int col0 = c0 + lc, col1 = c0 + 16 + lc;
            float m = -INFINITY;
            if (col0 < M) m = v0;
            if (col1 < M) m = fmaxf(m, v1);
            #pragma unroll
            for (int d = 1; d < 16; d <<= 1) m = fmaxf(m, __shfl_xor(m, d, 16));
            float dn = 0.f, S = 0.f, cnt = 0.f;
            #pragma unroll
            for (int jj = 0; jj < 2; ++jj) {
                int col = jj ? col1 : col0;
                float L = jj ? v1 : v0;
                if (col >= M) continue;
                if (!maskmode) {
                    if (col != row) {
                        dn += expf(L - m);
                        if (sl[col] == la) { S += L; cnt += 1.f; }
                    }
                } else {
                    int qq = col - n;
                    int qm = (col < n) ? col : (qq < n ? qq : qq - n);
                    bool tot = (sl[qm] == la) && (col >= n || col != row);
                    if (tot) { S += L; cnt += 1.f; }
                    else dn += expf(L - m);
                }
            }
            #pragma unroll
            for (int d = 1; d < 16; d <<= 1) {
                dn  += __shfl_xor(dn, d, 16);
                S   += __shfl_xor(S, d, 16);
                cnt += __shfl_xor(cnt, d, 16);
            }
            if (rok && lc == 0) part[(size_t)row*NR + ri] = make_float4(m, dn, S, cnt);
        }
    }
}

// ---------------- 6. combine partials -> per-anchor losses ----------------
__global__ void k_combine(const int* __restrict__ meta, const float4* __restrict__ pfp,
                          const float4* __restrict__ pmp, float* __restrict__ paf,
                          float* __restrict__ pam) {
    int r = blockIdx.x*256 + threadIdx.x;
    int n = meta[2];
    if (r >= n) return;
    // feat
    {
        int nr = (n + 31) >> 5;
        float mg = -INFINITY;
        for (int i = 0; i < nr; ++i) mg = fmaxf(mg, pfp[(size_t)r*NRF_ + i].x);
        float dn = 0.f, S = 0.f, cnt = 0.f;
        for (int i = 0; i < nr; ++i) {
            float4 p = pfp[(size_t)r*NRF_ + i];
            dn += p.y * expf(p.x - mg);
            S += p.z; cnt += p.w;
        }
        float lg = logf(dn + 1e-16f);
        paf[r] = (S - cnt*mg - cnt*lg) / (cnt + 1e-16f);
    }
    // mask
    {
        int nr = (3*n + 31) >> 5;
        float mg = -INFINITY;
        for (int i = 0; i < nr; ++i) mg = fmaxf(mg, pmp[(size_t)r*NRM_ + i].x);
        float dn = 0.f, S = 0.f, cnt = 0.f;
        for (int i = 0; i < nr; ++i) {
            float4 p = pmp[(size_t)r*NRM_ + i];
            dn += p.y * expf(p.x - mg);
            S += p.z; cnt += p.w;
        }
        float lg = logf(dn + 1e-16f);
        pam[r] = (S - cnt*mg - cnt*lg) / (cnt + 1e-16f);
    }
}

// ---------------- 7. finalize ----------------
__global__ void k_final(const int* __restrict__ meta, const float* __restrict__ paf,
                        const float* __restrict__ pam, float* __restrict__ out) {
    __shared__ float redf[4][2];
    int n = meta[2];
    int total = meta[0];
    int t = threadIdx.x, lane = t & 63, w = t >> 6;
    float sf = 0.f, sm = 0.f;
    for (int a = t; a < n; a += 256) { sf += paf[a]; sm += pam[a]; }
    #pragma unroll
    for (int d = 1; d < 64; d <<= 1) { sf += __shfl_xor(sf, d); sm += __shfl_xor(sm, d); }
    if (lane == 0) { redf[w][0] = sf; redf[w][1] = sm; }
    __syncthreads();
    if (t == 0) {
        sf = redf[0][0] + redf[1][0] + redf[2][0] + redf[3][0];
        sm = redf[0][1] + redf[1][1] + redf[2][1] + redf[3][1];
        if (total == 0 || n == 0) { out[0] = 0.f; out[1] = 0.f; }
        else {
            float scale = (float)(-(0.1/0.07));
            out[0] = scale * (sf / (float)n) * 0.1f;   // FEAT_W
            out[1] = scale * (sm / (float)n) * 0.1f;   // MASK_W
        }
    }
}

extern "C" void kernel_launch(void* const* d_in, const int* in_sizes, int n_in,
                              void* d_out, int out_size, void* d_ws, size_t ws_size,
                              hipStream_t stream) {
    const float* pf  = (const float*)d_in[0];   // proj_feats (B,C,H,W)
    const float* seg = (const float*)d_in[1];   // seg_logits (B,19,H,W)
    const int*   gt  = (const int*)d_in[2];     // groundtruth (B,1,H,W)
    const float* pm  = (const float*)d_in[3];   // proj_masks (3,B,256,H,W)
    float* out = (float*)d_out;
    char* ws = (char*)d_ws;

    int*   predict  = (int*)(ws + OFF_PREDICT);
    float* probc    = (float*)(ws + OFF_PROBC);
    int*   cnt_all  = (int*)(ws + OFF_CNT);
    int*   cnt_easy = cnt_all + NHIST_;
    int*   meta     = (int*)(ws + OFF_META);
    int*   pairs    = (int*)(ws + OFF_PAIRS);
    int*   sel_b    = (int*)(ws + OFF_SELB);
    int*   sel_p    = (int*)(ws + OFF_SELP);
    int*   sel_l    = (int*)(ws + OFF_SELL);
    unsigned short* sfh = (unsigned short*)(ws + OFF_SFH);
    unsigned short* km  = (unsigned short*)(ws + OFF_KMH);
    float* paf      = (float*)(ws + OFF_PAF);
    float* pam      = (float*)(ws + OFF_PAM);
    int*   lbase    = (int*)(ws + OFF_LBASE);
    int*   cursor   = (int*)(ws + OFF_CURS);
    int*   hista    = (int*)(ws + OFF_HISTA);
    int*   histe    = (int*)(ws + OFF_HISTE);
    float4* pfp     = (float4*)(ws + OFF_PFP);
    float4* pmp     = (float4*)(ws + OFF_PMP);
    unsigned long long* cand = (unsigned long long*)(ws + OFF_CAND);

    k_softmax_predict<<<NBLK_, 256, 0, stream>>>(seg, gt, predict, probc, hista, histe);
    k_plan<<<1, 256, 0, stream>>>(hista, histe, cnt_all, cnt_easy, meta, pairs, lbase, cursor);
    k_scatter<<<NBLK_, 256, 0, stream>>>(gt, predict, probc, lbase, cursor, cand);
    k_select2<<<NLIST_, 256, 0, stream>>>(cnt_all, cnt_easy, pairs, lbase, cand, sel_b, sel_p, sel_l);
    k_gather<<<MAXN_, 256, 0, stream>>>(pf, pm, meta, sel_b, sel_p, sfh, km);
    k_rows_mfma<<<dim3(MAXN_/64, 64), 256, 0, stream>>>(meta, sfh, km, sel_l, pfp, pmp);
    k_combine<<<(MAXN_ + 255)/256, 256, 0, stream>>>(meta, pfp, pmp, paf, pam);
    k_final<<<1, 256, 0, stream>>>(meta, paf, pam, out);
}

// Round 7
// 132.136 us; speedup vs baseline: 1.0549x; 1.0549x over previous
//
#include <hip/hip_runtime.h>
#include <hip/hip_bf16.h>
#include <math.h>

#define B_ 2
#define NCLS_ 19
#define N_ 25600
#define C_ 256
#define MAXN_ 1024
#define THRESH_ 100
#define MAXSAMP_ 1024
#define NLIST_ (B_*NCLS_*2)
#define NHIST_ (B_*NCLS_)
#define NBLK_ 200              // (B_*N_+255)/256
#define CAP_ 6144
#define CAPL_ 25600            // fixed capacity per candidate list
#define NRF_ 32                // feat key ranges (MAXN/32)
#define NRM_ 96                // mask key ranges (3*MAXN/32)

typedef __attribute__((ext_vector_type(8))) short bf16x8;
typedef __attribute__((ext_vector_type(4))) float f32x4;

// ---------------- workspace layout (bytes) ----------------
constexpr size_t OFF_CURS = 0;                                   // NLIST ints + finish counter (512 B, memset each call)
constexpr size_t OFF_SELB = 512;
constexpr size_t OFF_SELP = OFF_SELB + (size_t)MAXN_*4;
constexpr size_t OFF_SELL = OFF_SELP + (size_t)MAXN_*4;
constexpr size_t OFF_SFH  = OFF_SELL + (size_t)MAXN_*4;          // MAXN*C bf16
constexpr size_t OFF_KMH  = OFF_SFH + (size_t)MAXN_*C_*2;        // 3*MAXN*C bf16
constexpr size_t OFF_PAF  = OFF_KMH + (size_t)3*MAXN_*C_*2;
constexpr size_t OFF_PAM  = OFF_PAF + (size_t)MAXN_*4;
constexpr size_t OFF_PFP  = OFF_PAM + (size_t)MAXN_*4;           // MAXN*NRF float4
constexpr size_t OFF_PMP  = OFF_PFP + (size_t)MAXN_*NRF_*16;     // MAXN*NRM float4
constexpr size_t OFF_CAND = OFF_PMP + (size_t)MAXN_*NRM_*16;     // NLIST*CAPL u64 (~15.6 MB)

__device__ __forceinline__ unsigned short f2bf(float x) {
    unsigned u = __float_as_uint(x);
    unsigned r = (u + 0x7FFFu + ((u >> 16) & 1u)) >> 16;   // RNE
    return (unsigned short)r;
}

// ---- mining plan recomputed from cursor counts (cheap: 76 L2-hot ints) ----
__device__ __forceinline__ void plan_takes(int ne, int nh, int n_view, int* h, int* e) {
    int nhk, nek;
    bool hb = 2*nh >= n_view, eb = 2*ne >= n_view;
    if (hb && eb)      { nhk = n_view/2; nek = n_view - nhk; }
    else if (hb)       { nek = ne;       nhk = n_view - nek; }
    else if (eb)       { nhk = nh;       nek = n_view - nhk; }
    else               { nhk = nh;       nek = ne; }
    *h = nhk < nh ? nhk : nh;
    *e = nek < ne ? nek : ne;
}

__device__ __forceinline__ int plan_total_n(const int* __restrict__ cursor, int* o_total) {
    int total = 0;
    for (int i = 0; i < NHIST_; ++i)
        if (cursor[2*i] + cursor[2*i+1] > THRESH_) total++;
    int n_view = 0;
    if (total > 0) { n_view = MAXSAMP_ / total; if (n_view > THRESH_) n_view = THRESH_; }
    int off = 0;
    for (int i = 0; i < NHIST_; ++i) {
        int ne = cursor[2*i], nh = cursor[2*i+1];
        if (ne + nh > THRESH_) { int h, e; plan_takes(ne, nh, n_view, &h, &e); off += h + e; }
    }
    if (o_total) *o_total = total;
    return off;
}

__device__ __forceinline__ void plan_slot(const int* __restrict__ cursor, int slot,
                                          int* h_take, int* e_take, int* off_out) {
    int total = 0;
    for (int i = 0; i < NHIST_; ++i)
        if (cursor[2*i] + cursor[2*i+1] > THRESH_) total++;
    int n_view = 0;
    if (total > 0) { n_view = MAXSAMP_ / total; if (n_view > THRESH_) n_view = THRESH_; }
    int off = 0, ht = 0, et = 0, myoff = 0;
    for (int i = 0; i < NHIST_; ++i) {
        int ne = cursor[2*i], nh = cursor[2*i+1];
        int h = 0, e = 0;
        if (ne + nh > THRESH_) plan_takes(ne, nh, n_view, &h, &e);
        if (i == slot) { ht = h; et = e; myoff = off; }
        off += h + e;
    }
    *h_take = ht; *e_take = et; *off_out = myoff;
}

// ---------------- 1. fused softmax/argmax + candidate scatter ----------------
// cand list L = (b*NCLS+c)*2 + ishard, fixed base L*CAPL, count in cursor[L].
// No predict/probc round-trip; all register arrays statically indexed (no scratch).
__global__ void __launch_bounds__(256, 2)
k_softmax_scatter(const float* __restrict__ seg, const int* __restrict__ gt,
                  int* __restrict__ cursor, unsigned long long* __restrict__ cand) {
    __shared__ int lcnt[NLIST_];
    __shared__ int lbeg[NLIST_];
    int t = threadIdx.x;
    if (t < NLIST_) lcnt[t] = 0;
    __syncthreads();
    int idx = blockIdx.x * 256 + t;
    int L = -1, lp = 0;
    unsigned long long key = 0;
    if (idx < B_*N_) {
        int b = idx / N_, p = idx - b*N_;
        int lab = gt[idx];
        if (lab >= 0 && lab < NCLS_) {
            const float* base = seg + (size_t)b*NCLS_*N_ + p;
            float v[NCLS_];
            float mx = -INFINITY; int am = 0;
            #pragma unroll
            for (int k = 0; k < NCLS_; ++k) {
                float x = base[(size_t)k*N_];
                v[k] = x;
                if (x > mx) { mx = x; am = k; }
            }
            float ssum = 0.f, pv = 0.f;
            #pragma unroll
            for (int k = 0; k < NCLS_; ++k) {
                float e = expf(v[k] - mx);
                ssum += e;
                pv = (lab == k) ? e : pv;       // static index + cndmask, no scratch
            }
            pv /= ssum;
            int ishard = (am != lab) ? 1 : 0;
            L = (b*NCLS_ + lab)*2 + ishard;
            lp = atomicAdd(&lcnt[L], 1);
            unsigned int pb = __float_as_uint(pv);
            // hard: max-order = (desc prob, asc pixel) -> complement pixel; easy: plain
            unsigned int lo = ishard ? (0xFFFFFFFFu - (unsigned int)p) : (unsigned int)p;
            key = ((unsigned long long)pb << 32) | (unsigned long long)lo;
        }
    }
    __syncthreads();
    if (t < NLIST_ && lcnt[t] > 0) lbeg[t] = atomicAdd(&cursor[t], lcnt[t]);
    __syncthreads();
    if (L >= 0) cand[(size_t)L*CAPL_ + lbeg[L] + lp] = key;
}

// ---------------- 2. exact ordered top-k per list (plan recomputed per block) ----------------
__global__ void __launch_bounds__(256, 2)
k_select2(const int* __restrict__ cursor, const unsigned long long* __restrict__ cand,
          int* __restrict__ sel_b, int* __restrict__ sel_p, int* __restrict__ sel_l) {
    __shared__ unsigned long long keys[CAP_];
    __shared__ unsigned long long wpart[2][4];
    int bid = blockIdx.x;
    int slot = bid >> 1, ishard = bid & 1;
    int h_take, e_take, base_off;
    plan_slot(cursor, slot, &h_take, &e_take, &base_off);
    int take = ishard ? h_take : e_take;
    if (take == 0) return;
    int off = base_off + (ishard ? 0 : h_take);
    int m = cursor[2*slot + ishard];
    const unsigned long long* g = cand + (size_t)(2*slot + ishard)*CAPL_;
    int t = threadIdx.x, lane = t & 63, w = t >> 6;
    bool fits = (m <= CAP_);
    if (fits) {
        for (int j = t; j < m; j += 256) keys[j] = g[j];
        __syncthreads();
    }
    int b = slot / NCLS_, c = slot - b*NCLS_;
    unsigned long long prev = ishard ? 0xFFFFFFFFFFFFFFFFull : 0ull;
    for (int it = 0; it < take; ++it) {
        unsigned long long best = ishard ? 0ull : 0xFFFFFFFFFFFFFFFFull;
        if (ishard) {
            for (int j = t; j < m; j += 256) {
                unsigned long long k = fits ? keys[j] : g[j];
                if (k < prev && k > best) best = k;
            }
        } else {
            for (int j = t; j < m; j += 256) {
                unsigned long long k = fits ? keys[j] : g[j];
                if (k > prev && k < best) best = k;
            }
        }
        #pragma unroll
        for (int d = 1; d < 64; d <<= 1) {
            unsigned long long o = __shfl_xor(best, d);
            if (ishard ? (o > best) : (o < best)) best = o;
        }
        if (lane == 0) wpart[it & 1][w] = best;
        __syncthreads();
        unsigned long long b0 = wpart[it & 1][0], b1 = wpart[it & 1][1];
        unsigned long long b2 = wpart[it & 1][2], b3 = wpart[it & 1][3];
        if (ishard) {
            unsigned long long hi01 = b0 > b1 ? b0 : b1;
            unsigned long long hi23 = b2 > b3 ? b2 : b3;
            prev = hi01 > hi23 ? hi01 : hi23;
        } else {
            unsigned long long lo01 = b0 < b1 ? b0 : b1;
            unsigned long long lo23 = b2 < b3 ? b2 : b3;
            prev = lo01 < lo23 ? lo01 : lo23;
        }
        if (t == 0) {
            unsigned int lo = (unsigned int)(prev & 0xFFFFFFFFull);
            int p = ishard ? (int)(0xFFFFFFFFu - lo) : (int)lo;
            sel_b[off+it] = b; sel_p[off+it] = p; sel_l[off+it] = c;
        }
    }
}

// ---------------- 3. gather + l2-normalize -> bf16 (1 wave / vector, no barriers) ----------------
__global__ void __launch_bounds__(64)
k_gather(const float* __restrict__ pf, const float* __restrict__ pm,
         const int* __restrict__ cursor, const int* __restrict__ sel_b,
         const int* __restrict__ sel_p,
         unsigned short* __restrict__ sfh, unsigned short* __restrict__ km) {
    int bid = blockIdx.x;
    int s = bid >> 2, vec = bid & 3;
    int n = plan_total_n(cursor, nullptr);
    if (s >= n) return;
    int b = sel_b[s], p = sel_p[s];
    int lane = threadIdx.x;
    const float* src;
    unsigned short* dst;
    if (vec == 0)      { src = pf + (size_t)(b*C_)*N_ + p;          dst = sfh + (size_t)s*C_; }
    else if (vec == 1) { src = pm + (size_t)((2*B_+b)*C_)*N_ + p;   dst = km + (size_t)s*C_; }            // anchor
    else if (vec == 2) { src = pm + (size_t)((0*B_+b)*C_)*N_ + p;   dst = km + (size_t)(n + 2*s)*C_; }    // key 0
    else               { src = pm + (size_t)((1*B_+b)*C_)*N_ + p;   dst = km + (size_t)(n + 2*s + 1)*C_; }// key 1
    float x[4]; float ss = 0.f;
    #pragma unroll
    for (int q = 0; q < 4; ++q) { x[q] = src[(size_t)(lane + 64*q)*N_]; ss += x[q]*x[q]; }
    #pragma unroll
    for (int d = 1; d < 64; d <<= 1) ss += __shfl_xor(ss, d);
    float inv = 1.f / fmaxf(sqrtf(ss), 1e-12f);
    #pragma unroll
    for (int q = 0; q < 4; ++q) dst[lane + 64*q] = f2bf(x[q] * inv);
}

// ---------------- 4. fused MFMA GEMM + masked-softmax partials ----------------
// blockIdx.y < 16 : feat  (A=B=sfh, M=n,  part=pfp, NR=32)
// blockIdx.y >= 16: mask  (A=B=km,  M=3n, part=pmp, NR=96)
__global__ void __launch_bounds__(256, 4)
k_rows_mfma(const int* __restrict__ cursor, const unsigned short* __restrict__ sfh,
            const unsigned short* __restrict__ km, const int* __restrict__ sel_l,
            float4* __restrict__ pfp, float4* __restrict__ pmp) {
    const int n = plan_total_n(cursor, nullptr);
    const bool maskmode = (blockIdx.y >= 16);
    const int yb = maskmode ? (blockIdx.y - 16) : blockIdx.y;
    const int M = maskmode ? 3*n : n;
    const int rbase = blockIdx.x * 64;
    const int cbase = yb * 64;
    if (rbase >= n || cbase >= M) return;
    const unsigned short* buf = maskmode ? km : sfh;
    float4* part = maskmode ? pmp : pfp;
    const int NR = maskmode ? NRM_ : NRF_;

    __shared__ int sl[MAXN_];
    const int t = threadIdx.x;
    for (int j = t; j < n; j += 256) sl[j] = sel_l[j];
    __syncthreads();

    const int wid = t >> 6, lane = t & 63;
    const int wr = wid >> 1, wc = wid & 1;
    const int r0 = rbase + wr*32;
    const int c0 = cbase + wc*32;
    const int lrow = lane & 15, lk = (lane >> 4) * 8;

    const bf16x8 zero8 = {0,0,0,0,0,0,0,0};
    f32x4 acc[2][2];
    #pragma unroll
    for (int i = 0; i < 2; ++i)
        #pragma unroll
        for (int j = 0; j < 2; ++j) acc[i][j] = (f32x4){0.f,0.f,0.f,0.f};

    for (int kk = 0; kk < C_; kk += 32) {
        bf16x8 af[2], bfr[2];
        #pragma unroll
        for (int i = 0; i < 2; ++i) {
            int r = r0 + i*16 + lrow;
            af[i] = (r < n) ? *(const bf16x8*)&buf[(size_t)r*C_ + kk + lk] : zero8;
        }
        #pragma unroll
        for (int j = 0; j < 2; ++j) {
            int c = c0 + j*16 + lrow;
            bfr[j] = (c < M) ? *(const bf16x8*)&buf[(size_t)c*C_ + kk + lk] : zero8;
        }
        #pragma unroll
        for (int i = 0; i < 2; ++i)
            #pragma unroll
            for (int j = 0; j < 2; ++j)
                acc[i][j] = __builtin_amdgcn_mfma_f32_16x16x32_bf16(af[i], bfr[j], acc[i][j], 0, 0, 0);
    }

    // epilogue: C layout: col = lane&15 (+j*16), row = (lane>>4)*4 + reg (+i*16)
    const int ri = yb*2 + wc;
    const int g4 = (lane >> 4) * 4;
    const int lc = lane & 15;
    #pragma unroll
    for (int i = 0; i < 2; ++i) {
        #pragma unroll
        for (int q = 0; q < 4; ++q) {
            int row = r0 + i*16 + g4 + q;
            bool rok = (row < n);
            int la = rok ? sl[row] : 0;
            float v0 = acc[i][0][q] * 10.0f;
            float v1 = acc[i][1][q] * 10.0f;
            int col0 = c0 + lc, col1 = c0 + 16 + lc;
            float m = -INFINITY;
            if (col0 < M) m = v0;
            if (col1 < M) m = fmaxf(m, v1);
            #pragma unroll
            for (int d = 1; d < 16; d <<= 1) m = fmaxf(m, __shfl_xor(m, d, 16));
            float dn = 0.f, S = 0.f, cnt = 0.f;
            #pragma unroll
            for (int jj = 0; jj < 2; ++jj) {
                int col = jj ? col1 : col0;
                float L = jj ? v1 : v0;
                if (col >= M) continue;
                if (!maskmode) {
                    if (col != row) {
                        dn += expf(L - m);
                        if (sl[col] == la) { S += L; cnt += 1.f; }
                    }
                } else {
                    int qq = col - n;
                    int qm = (col < n) ? col : (qq < n ? qq : qq - n);
                    bool tot = (sl[qm] == la) && (col >= n || col != row);
                    if (tot) { S += L; cnt += 1.f; }
                    else dn += expf(L - m);
                }
            }
            #pragma unroll
            for (int d = 1; d < 16; d <<= 1) {
                dn  += __shfl_xor(dn, d, 16);
                S   += __shfl_xor(S, d, 16);
                cnt += __shfl_xor(cnt, d, 16);
            }
            if (rok && lc == 0) part[(size_t)row*NR + ri] = make_float4(m, dn, S, cnt);
        }
    }
}

// ---------------- 5. combine partials + final reduce (last-block pattern) ----------------
__global__ void __launch_bounds__(256, 2)
k_combine_final(const int* __restrict__ cursor, const float4* __restrict__ pfp,
                const float4* __restrict__ pmp, float* __restrict__ paf,
                float* __restrict__ pam, int* __restrict__ counter,
                float* __restrict__ out) {
    int total;
    int n = plan_total_n(cursor, &total);
    int t = threadIdx.x;
    int r = blockIdx.x*256 + t;
    if (r < n) {
        {   // feat
            int nr = (n + 31) >> 5;
            float mg = -INFINITY;
            for (int i = 0; i < nr; ++i) mg = fmaxf(mg, pfp[(size_t)r*NRF_ + i].x);
            float dn = 0.f, S = 0.f, cnt = 0.f;
            for (int i = 0; i < nr; ++i) {
                float4 p = pfp[(size_t)r*NRF_ + i];
                dn += p.y * expf(p.x - mg);
                S += p.z; cnt += p.w;
            }
            float lg = logf(dn + 1e-16f);
            paf[r] = (S - cnt*mg - cnt*lg) / (cnt + 1e-16f);
        }
        {   // mask
            int nr = (3*n + 31) >> 5;
            float mg = -INFINITY;
            for (int i = 0; i < nr; ++i) mg = fmaxf(mg, pmp[(size_t)r*NRM_ + i].x);
            float dn = 0.f, S = 0.f, cnt = 0.f;
            for (int i = 0; i < nr; ++i) {
                float4 p = pmp[(size_t)r*NRM_ + i];
                dn += p.y * expf(p.x - mg);
                S += p.z; cnt += p.w;
            }
            float lg = logf(dn + 1e-16f);
            pam[r] = (S - cnt*mg - cnt*lg) / (cnt + 1e-16f);
        }
    }
    __threadfence();
    __shared__ int amLast;
    if (t == 0) amLast = (atomicAdd(counter, 1) == (int)gridDim.x - 1);
    __syncthreads();
    if (!amLast) return;
    __threadfence();
    __shared__ float redf[4][2];
    int lane = t & 63, w = t >> 6;
    float sf = 0.f, sm = 0.f;
    for (int a = t; a < n; a += 256) { sf += paf[a]; sm += pam[a]; }
    #pragma unroll
    for (int d = 1; d < 64; d <<= 1) { sf += __shfl_xor(sf, d); sm += __shfl_xor(sm, d); }
    if (lane == 0) { redf[w][0] = sf; redf[w][1] = sm; }
    __syncthreads();
    if (t == 0) {
        sf = redf[0][0] + redf[1][0] + redf[2][0] + redf[3][0];
        sm = redf[0][1] + redf[1][1] + redf[2][1] + redf[3][1];
        if (total == 0 || n == 0) { out[0] = 0.f; out[1] = 0.f; }
        else {
            float scale = (float)(-(0.1/0.07));
            out[0] = scale * (sf / (float)n) * 0.1f;   // FEAT_W
            out[1] = scale * (sm / (float)n) * 0.1f;   // MASK_W
        }
    }
}

extern "C" void kernel_launch(void* const* d_in, const int* in_sizes, int n_in,
                              void* d_out, int out_size, void* d_ws, size_t ws_size,
                              hipStream_t stream) {
    const float* pf  = (const float*)d_in[0];   // proj_feats (B,C,H,W)
    const float* seg = (const float*)d_in[1];   // seg_logits (B,19,H,W)
    const int*   gt  = (const int*)d_in[2];     // groundtruth (B,1,H,W)
    const float* pm  = (const float*)d_in[3];   // proj_masks (3,B,256,H,W)
    float* out = (float*)d_out;
    char* ws = (char*)d_ws;

    int*   cursor   = (int*)(ws + OFF_CURS);
    int*   counter  = cursor + NLIST_;
    int*   sel_b    = (int*)(ws + OFF_SELB);
    int*   sel_p    = (int*)(ws + OFF_SELP);
    int*   sel_l    = (int*)(ws + OFF_SELL);
    unsigned short* sfh = (unsigned short*)(ws + OFF_SFH);
    unsigned short* km  = (unsigned short*)(ws + OFF_KMH);
    float* paf      = (float*)(ws + OFF_PAF);
    float* pam      = (float*)(ws + OFF_PAM);
    float4* pfp     = (float4*)(ws + OFF_PFP);
    float4* pmp     = (float4*)(ws + OFF_PMP);
    unsigned long long* cand = (unsigned long long*)(ws + OFF_CAND);

    hipMemsetAsync(ws + OFF_CURS, 0, 512, stream);   // cursors + finish counter

    k_softmax_scatter<<<NBLK_, 256, 0, stream>>>(seg, gt, cursor, cand);
    k_select2<<<NLIST_, 256, 0, stream>>>(cursor, cand, sel_b, sel_p, sel_l);
    k_gather<<<4*MAXN_, 64, 0, stream>>>(pf, pm, cursor, sel_b, sel_p, sfh, km);
    k_rows_mfma<<<dim3(MAXN_/64, 64), 256, 0, stream>>>(cursor, sfh, km, sel_l, pfp, pmp);
    k_combine_final<<<(MAXN_ + 255)/256, 256, 0, stream>>>(cursor, pfp, pmp, paf, pam, counter, out);
}